// Round 7
// baseline (1173.167 us; speedup 1.0000x reference)
//
#include <hip/hip_runtime.h>
#include <hip/hip_bf16.h>

// TFSwinSelfAttention fused kernel for MI355X (gfx950).
// Shapes: B=4096 windows, N=49 tokens, D=256 = 8 heads x 32.
// fp32 in/out; internal bf16 MFMA compute (fp32 accum) within harness tol.
//
// Round-9 (register-TOTAL occupancy fix):
//   Reconciling r1..r6 counters with the gfx950 occupancy steps (per-SIMD
//   pool = 512 per-wave regs) shows rocprof's VGPR_Count is ARCH-only;
//   AGPR accumulators share the unified file. r4/r5/r6: arch 176-228 +
//   ~64-96 AGPR > 256 total -> 1 wave/SIMD (Occ 12%) regardless of LDS.
//   r1's (128,2) correctly budgeted 256 total (128 arch + 128 acc); its
//   spill was the long-gone 128-reg afr cache not fitting 128 arch.
//   r6's streamed structure has arch-live ~100-130 (projection acc lives
//   on the acc side as MFMA accumulators), so the budget now fits.
//   SINGLE CHANGE vs r6: __launch_bounds__(256) -> (256, 2).
//   Watch: WRITE_SIZE > 200,704 KB => arch side spilled (r1 precedent:
//   even 126 MB of spill still nets the occupancy win).
//
// Carried from r6/r7/r8:
//   - 256-thread blocks (4 waves), wave w does heads {w, w+4}.
//   - Window staged once/block to LDS bf16 (xb, swizzled); A-frags streamed
//     per-kk via ds_read_b128; projection split q/k-pass + v-pass.
//   - Per-wave XOR-swizzled bufs: q/k[64][32], P[64][64] overlays q+k,
//     vt[32][64]; mask read from global fp32 (coalesced, L1-hot).
//   - Streamed per-16-row tail: scores -> softmax -> PV -> store.
//   - Single block barrier; end-of-head lgkmcnt fence for the WAR hazard.

typedef __bf16 bf16;
typedef __attribute__((ext_vector_type(8))) __bf16 bf16x8;
typedef __attribute__((ext_vector_type(4))) float f32x4;

__device__ __forceinline__ f32x4 mfma16(bf16x8 a, bf16x8 b, f32x4 c) {
    return __builtin_amdgcn_mfma_f32_16x16x32_bf16(a, b, c, 0, 0, 0);
}

// --------------------------------------------------------------------------
// Kernel 0: repack fp32 weights into bf16 B-fragment order (unchanged).
// packed[((t*16 + nt)*8 + kk)*512 + L*8 + j] = W_t[kk*32 + (L>>4)*8 + j][nt*16 + (L&15)]
__global__ void repack_w(const float* __restrict__ wq, const float* __restrict__ wk,
                         const float* __restrict__ wv, bf16* __restrict__ pk) {
    int i = blockIdx.x * 256 + threadIdx.x;      // 0 .. 3*65536-1
    int t = i >> 16;
    int r = i & 65535;
    int kr = r >> 8, nc = r & 255;
    const float* w = (t == 0) ? wq : (t == 1) ? wk : wv;
    int nt = nc >> 4;
    int kk = kr >> 5;
    int Ln = (((kr >> 3) & 3) << 4) | (nc & 15);
    int j  = kr & 7;
    pk[(((t * 16 + nt) * 8 + kk) << 9) + Ln * 8 + j] = (bf16)w[r];
}

// --------------------------------------------------------------------------
#define NTOK 49
#define SCALE 0.17677669529663687f   // 1/sqrt(32)

// LDS blob layout (bytes).
#define XB_BASE   0            // bf16[49][256] swizzled  = 25,088
#define WB_BASE   25088        // 4 waves x 12,288        = 49,152
#define WB_SIZE   12288
#define QOFF      0            // bf16[64][32] swz        =  4,096
#define KOFF      4096         // bf16[64][32] swz        =  4,096
#define POFF      0            // bf16[64][64] swz, overlays q+k = 8,192
#define VTOFF     8192         // bf16[32][64] swz        =  4,096
#define TAB_BASE  74240        // bf16[1352]              =  2,704
#define SMEM_BYTES 76944       // 2 blocks/CU with >=7KB slack at any granule

// swizzle: byte ^= ((row&7)<<4); 16B granules move atomically.
#define XB_OFF(r,c)      (XB_BASE + ((((r) << 9) + ((c) << 1)) ^ (((r) & 7) << 4)))
#define QK_OFF(base,r,d) ((base) + ((((r) << 6) + ((d) << 1)) ^ (((r) & 7) << 4)))
#define P_OFF(base,r,c)  ((base) + ((((r) << 7) + ((c) << 1)) ^ (((r) & 7) << 4)))
#define VT_OFF(base,d,t) ((base) + ((((d) << 7) + ((t) << 1)) ^ (((d) & 7) << 4)))

__global__ __launch_bounds__(256, 2)   // 2 waves/EU: total (arch+acc) budget 256/wave
void swin_attn(
    const float* __restrict__ hidden, const float* __restrict__ mask_g,
    const float* __restrict__ bq_g, const float* __restrict__ bk_g,
    const float* __restrict__ bv_g, const float* __restrict__ table_g,
    const bf16* __restrict__ pkw, float* __restrict__ out)
{
    __shared__ __align__(16) unsigned char sm[SMEM_BYTES];

    const int tid  = threadIdx.x;
    const int b    = blockIdx.x;
    const int widx = b & 63;
    const float* hbase = hidden + (size_t)b * (NTOK * 256);
    const float* mbase = mask_g + widx * 2401;

    // ---- cooperative staging: x window fp32->bf16 (swizzled), tab -------
    for (int c4 = tid; c4 < 3136; c4 += 256) {      // 49*256/4 chunks
        int row = c4 >> 6;
        int col = (c4 & 63) << 2;                   // 8B-aligned dest
        f32x4 v = *(const f32x4*)(hbase + row * 256 + col);
        union { bf16 h[4]; unsigned long long u; } p;
        p.h[0] = (bf16)v[0]; p.h[1] = (bf16)v[1];
        p.h[2] = (bf16)v[2]; p.h[3] = (bf16)v[3];
        *(unsigned long long*)(sm + XB_OFF(row, col)) = p.u;
    }
    for (int i = tid; i < 1352; i += 256)
        *(bf16*)(sm + TAB_BASE + 2 * i) = (bf16)table_g[i];
    __syncthreads();   // the ONLY block-wide barrier

    const int wave = tid >> 6;
    const int L    = tid & 63;
    const int quad = L >> 4;
    const int cc   = L & 15;
    const int WB   = WB_BASE + wave * WB_SIZE;

    // ---- geometry: rel-pos linear coords per lane ----------------------
    int pr[16];
#pragma unroll
    for (int mt = 0; mt < 4; ++mt)
#pragma unroll
        for (int j = 0; j < 4; ++j) {
            int r = 16 * mt + 4 * quad + j;
            int rh = (r * 9363) >> 16;          // r / 7 for r < 64
            pr[mt * 4 + j] = 13 * rh + (r - 7 * rh);
        }
    int pc[4];
#pragma unroll
    for (int nt = 0; nt < 4; ++nt) {
        int c = 16 * nt + cc;
        int ch = (c * 9363) >> 16;
        pc[nt] = 13 * ch + (c - 7 * ch);
    }

    int arow[4];
#pragma unroll
    for (int mt = 0; mt < 4; ++mt) {
        int r = 16 * mt + cc;
        arow[mt] = (r > 48) ? 48 : r;           // clamped rows discarded later
    }

    // ---- per-head pipeline: wave w -> heads {w, w+4} -------------------
    for (int hp = 0; hp < 2; ++hp) {
        const int h = wave + 4 * hp;

        float bqv[2], bkv[2], bvv[2];
#pragma unroll
        for (int hf = 0; hf < 2; ++hf) {
            bqv[hf] = bq_g[h * 32 + hf * 16 + cc];
            bkv[hf] = bk_g[h * 32 + hf * 16 + cc];
            bvv[hf] = bv_g[h * 32 + hf * 16 + cc];
        }

        // ---- pass A: q,k projection (kk-outer; acc = 64 regs, acc-side) -
        {
            f32x4 acc[2][2][4];
#pragma unroll
            for (int t = 0; t < 2; ++t)
#pragma unroll
                for (int hf = 0; hf < 2; ++hf)
#pragma unroll
                    for (int mt = 0; mt < 4; ++mt)
                        acc[t][hf][mt] = (f32x4){0.f, 0.f, 0.f, 0.f};
            const bf16* bpp[2][2];
#pragma unroll
            for (int t = 0; t < 2; ++t)
#pragma unroll
                for (int hf = 0; hf < 2; ++hf)
                    bpp[t][hf] = pkw + (((t * 16 + (h * 2 + hf)) * 8) << 9) + L * 8;
#pragma unroll 2
            for (int kk = 0; kk < 8; ++kk) {
                bf16x8 a[4];
#pragma unroll
                for (int mt = 0; mt < 4; ++mt)
                    a[mt] = *(const bf16x8*)(sm + XB_OFF(arow[mt], kk * 32 + quad * 8));
#pragma unroll
                for (int t = 0; t < 2; ++t)
#pragma unroll
                    for (int hf = 0; hf < 2; ++hf) {
                        bf16x8 bfv = *(const bf16x8*)(bpp[t][hf] + (kk << 9));
#pragma unroll
                        for (int mt = 0; mt < 4; ++mt)
                            acc[t][hf][mt] = mfma16(a[mt], bfv, acc[t][hf][mt]);
                    }
            }
#pragma unroll
            for (int t = 0; t < 2; ++t)
#pragma unroll
                for (int hf = 0; hf < 2; ++hf) {
                    const int d = hf * 16 + cc;
                    const int base = WB + (t == 0 ? QOFF : KOFF);
                    const float bias = (t == 0 ? bqv[hf] : bkv[hf]);
#pragma unroll
                    for (int mt = 0; mt < 4; ++mt)
#pragma unroll
                        for (int j = 0; j < 4; ++j) {
                            int row = 16 * mt + 4 * quad + j;
                            *(bf16*)(sm + QK_OFF(base, row, d)) =
                                (bf16)(acc[t][hf][mt][j] + bias);
                        }
                }
        }

        // ---- pass B: v projection (acc = 32 regs) ----------------------
        {
            f32x4 acc[2][4];
#pragma unroll
            for (int hf = 0; hf < 2; ++hf)
#pragma unroll
                for (int mt = 0; mt < 4; ++mt)
                    acc[hf][mt] = (f32x4){0.f, 0.f, 0.f, 0.f};
            const bf16* bpp[2];
#pragma unroll
            for (int hf = 0; hf < 2; ++hf)
                bpp[hf] = pkw + (((2 * 16 + (h * 2 + hf)) * 8) << 9) + L * 8;
#pragma unroll 2
            for (int kk = 0; kk < 8; ++kk) {
                bf16x8 a[4];
#pragma unroll
                for (int mt = 0; mt < 4; ++mt)
                    a[mt] = *(const bf16x8*)(sm + XB_OFF(arow[mt], kk * 32 + quad * 8));
#pragma unroll
                for (int hf = 0; hf < 2; ++hf) {
                    bf16x8 bfv = *(const bf16x8*)(bpp[hf] + (kk << 9));
#pragma unroll
                    for (int mt = 0; mt < 4; ++mt)
                        acc[hf][mt] = mfma16(a[mt], bfv, acc[hf][mt]);
                }
            }
#pragma unroll
            for (int hf = 0; hf < 2; ++hf) {
                const int d = hf * 16 + cc;
#pragma unroll
                for (int mt = 0; mt < 4; ++mt)
#pragma unroll
                    for (int j = 0; j < 4; ++j) {
                        int row = 16 * mt + 4 * quad + j;
                        *(bf16*)(sm + VT_OFF(WB + VTOFF, d, row)) =
                            (bf16)(acc[hf][mt][j] + bvv[hf]);
                    }
            }
        }

        // ---- preload fragments: q/k fully into regs (enables P overlay),
        //      v-frags reused across all mt ------------------------------
        bf16x8 aq[4], bkf[4], bvf[2][2];
#pragma unroll
        for (int mt = 0; mt < 4; ++mt)
            aq[mt] = *(const bf16x8*)(sm + QK_OFF(WB + QOFF, 16 * mt + cc, quad * 8));
#pragma unroll
        for (int nt = 0; nt < 4; ++nt)
            bkf[nt] = *(const bf16x8*)(sm + QK_OFF(WB + KOFF, 16 * nt + cc, quad * 8));
#pragma unroll
        for (int kk = 0; kk < 2; ++kk)
#pragma unroll
            for (int nt = 0; nt < 2; ++nt)
                bvf[kk][nt] = *(const bf16x8*)(sm + VT_OFF(WB + VTOFF, 16 * nt + cc,
                                                           kk * 32 + quad * 8));

        // ---- streamed per-16-row-block: scores -> softmax -> PV -> store
        float* op = out + (size_t)b * (NTOK * 256) + h * 32;
        const f32x4 z = (f32x4){0.f, 0.f, 0.f, 0.f};
#pragma unroll
        for (int mt = 0; mt < 4; ++mt) {
            f32x4 s[4];
#pragma unroll
            for (int nt = 0; nt < 4; ++nt)
                s[nt] = mfma16(aq[mt], bkf[nt], z);

            float linv[4];
#pragma unroll
            for (int j = 0; j < 4; ++j) {
                const int r = 16 * mt + 4 * quad + j;
                const float* mrow = mbase + r * 49;
                float vals[4];
#pragma unroll
                for (int nt = 0; nt < 4; ++nt) {
                    const int c = 16 * nt + cc;
                    float sc = s[nt][j] * SCALE;
                    if (r < 49 && c < 49) {
                        int idx = pr[mt * 4 + j] - pc[nt] + 84;
                        sc += (float)*(const bf16*)(sm + TAB_BASE + ((idx << 3) + h) * 2)
                            + mrow[c];                       // global fp32, L1-hot
                    } else {
                        sc = -1e30f;
                    }
                    vals[nt] = sc;
                }
                float mx = fmaxf(fmaxf(vals[0], vals[1]), fmaxf(vals[2], vals[3]));
                mx = fmaxf(mx, __shfl_xor(mx, 1));
                mx = fmaxf(mx, __shfl_xor(mx, 2));
                mx = fmaxf(mx, __shfl_xor(mx, 4));
                mx = fmaxf(mx, __shfl_xor(mx, 8));
                float sum = 0.f;
#pragma unroll
                for (int nt = 0; nt < 4; ++nt) {
                    float e = __expf(vals[nt] - mx);   // masked cols -> 0
                    sum += e;
                    *(bf16*)(sm + P_OFF(WB + POFF, r, 16 * nt + cc)) = (bf16)e;
                }
                sum += __shfl_xor(sum, 1);
                sum += __shfl_xor(sum, 2);
                sum += __shfl_xor(sum, 4);
                sum += __shfl_xor(sum, 8);
                linv[j] = 1.0f / sum;
            }

            // PV for this 16-row block (P rows 16mt..16mt+15 complete;
            // same-wave ds_write->ds_read ordered by compiler lgkmcnt)
            bf16x8 ap0 = *(const bf16x8*)(sm + P_OFF(WB + POFF, 16 * mt + cc, quad * 8));
            bf16x8 ap1 = *(const bf16x8*)(sm + P_OFF(WB + POFF, 16 * mt + cc, 32 + quad * 8));
            f32x4 o0 = z, o1 = z;
            o0 = mfma16(ap0, bvf[0][0], o0);
            o1 = mfma16(ap0, bvf[0][1], o1);
            o0 = mfma16(ap1, bvf[1][0], o0);
            o1 = mfma16(ap1, bvf[1][1], o1);

#pragma unroll
            for (int j = 0; j < 4; ++j) {
                const int r = 16 * mt + 4 * quad + j;
                if (r < 49) {
                    op[(size_t)r * 256 + cc]      = o0[j] * linv[j];
                    op[(size_t)r * 256 + 16 + cc] = o1[j] * linv[j];
                }
            }
        }
        // Fence the WAR hazard: next head's projection ds_writes must not
        // pass this head's P/vt ds_reads.
        asm volatile("s_waitcnt lgkmcnt(0)" ::: "memory");
    }
}

// --------------------------------------------------------------------------
extern "C" void kernel_launch(void* const* d_in, const int* in_sizes, int n_in,
                              void* d_out, int out_size, void* d_ws, size_t ws_size,
                              hipStream_t stream) {
    const float* hidden = (const float*)d_in[0];   // [4096,49,256]
    const float* mask   = (const float*)d_in[1];   // [64,49,49]
    const float* wq     = (const float*)d_in[2];   // [256,256]
    const float* bq     = (const float*)d_in[3];   // [256]
    const float* wk     = (const float*)d_in[4];
    const float* bk     = (const float*)d_in[5];
    const float* wv     = (const float*)d_in[6];
    const float* bv     = (const float*)d_in[7];
    const float* tab    = (const float*)d_in[8];   // [169,8]
    float* out = (float*)d_out;
    bf16* pkw = (bf16*)d_ws;                       // 393,216 B repacked weights

    repack_w<<<768, 256, 0, stream>>>(wq, wk, wv, pkw);
    swin_attn<<<4096, 256, 0, stream>>>(hidden, mask, bq, bk, bv, tab, pkw, out);
}

// Round 8
// 1002.861 us; speedup vs baseline: 1.1698x; 1.1698x over previous
//
#include <hip/hip_runtime.h>
#include <hip/hip_bf16.h>

// TFSwinSelfAttention fused kernel for MI355X (gfx950).
// Shapes: B=4096 windows, N=49 tokens, D=256 = 8 heads x 32.
// fp32 in/out; internal bf16 MFMA compute (fp32 accum) within harness tol.
//
// Round-10 (fit the 256-total register budget honestly):
//   r7 proved both halves of the model: (256,2) delivers 2 waves/SIMD
//   (Occ 22.7) with arch clamped to 128, but r6's structure needs ~290+
//   total regs -> 532 MB of per-loop scratch spill (WRITE 733 MB) -> 950us,
//   worse than plain-bounds' 1-wave 748us. So: KEEP (256,2), and cut ~80
//   regs of peak live state so it genuinely fits:
//   1. 3-pass projection (q, k, v separate): pass-peak acc 64 -> 32 regs.
//      A-frags re-read 3x from LDS (cheap); MFMA count unchanged.
//   2. pr[16]/pc[4] geometry arrays (20 persistent VGPRs) -> inline
//      recompute per use (~3 VALU, off the LDS/MFMA critical path).
//   Watch: WRITE_SIZE == 200,704 KB (no spill) is the success criterion;
//   Occ should hold ~22.
//
// Carried: window staged once/block to LDS bf16 (swizzled); per-wave
// XOR-swizzled q/k[64][32], P[64][64] overlays q+k, vt[32][64]; mask from
// global fp32 (coalesced, L1-hot); streamed per-16-row tail; single block
// barrier; end-of-head lgkmcnt fence for the WAR hazard.

typedef __bf16 bf16;
typedef __attribute__((ext_vector_type(8))) __bf16 bf16x8;
typedef __attribute__((ext_vector_type(4))) float f32x4;

__device__ __forceinline__ f32x4 mfma16(bf16x8 a, bf16x8 b, f32x4 c) {
    return __builtin_amdgcn_mfma_f32_16x16x32_bf16(a, b, c, 0, 0, 0);
}

// --------------------------------------------------------------------------
// Kernel 0: repack fp32 weights into bf16 B-fragment order (unchanged).
// packed[((t*16 + nt)*8 + kk)*512 + L*8 + j] = W_t[kk*32 + (L>>4)*8 + j][nt*16 + (L&15)]
__global__ void repack_w(const float* __restrict__ wq, const float* __restrict__ wk,
                         const float* __restrict__ wv, bf16* __restrict__ pk) {
    int i = blockIdx.x * 256 + threadIdx.x;      // 0 .. 3*65536-1
    int t = i >> 16;
    int r = i & 65535;
    int kr = r >> 8, nc = r & 255;
    const float* w = (t == 0) ? wq : (t == 1) ? wk : wv;
    int nt = nc >> 4;
    int kk = kr >> 5;
    int Ln = (((kr >> 3) & 3) << 4) | (nc & 15);
    int j  = kr & 7;
    pk[(((t * 16 + nt) * 8 + kk) << 9) + Ln * 8 + j] = (bf16)w[r];
}

// --------------------------------------------------------------------------
#define NTOK 49
#define SCALE 0.17677669529663687f   // 1/sqrt(32)

// LDS blob layout (bytes).
#define XB_BASE   0            // bf16[49][256] swizzled  = 25,088
#define WB_BASE   25088        // 4 waves x 12,288        = 49,152
#define WB_SIZE   12288
#define QOFF      0            // bf16[64][32] swz        =  4,096
#define KOFF      4096         // bf16[64][32] swz        =  4,096
#define POFF      0            // bf16[64][64] swz, overlays q+k = 8,192
#define VTOFF     8192         // bf16[32][64] swz        =  4,096
#define TAB_BASE  74240        // bf16[1352]              =  2,704
#define SMEM_BYTES 76944       // 2 blocks/CU with >=7KB slack

// swizzle: byte ^= ((row&7)<<4); 16B granules move atomically.
#define XB_OFF(r,c)      (XB_BASE + ((((r) << 9) + ((c) << 1)) ^ (((r) & 7) << 4)))
#define QK_OFF(base,r,d) ((base) + ((((r) << 6) + ((d) << 1)) ^ (((r) & 7) << 4)))
#define P_OFF(base,r,c)  ((base) + ((((r) << 7) + ((c) << 1)) ^ (((r) & 7) << 4)))
#define VT_OFF(base,d,t) ((base) + ((((d) << 7) + ((t) << 1)) ^ (((d) & 7) << 4)))

__global__ __launch_bounds__(256, 2)   // 2 waves/EU: 256-total budget per wave
void swin_attn(
    const float* __restrict__ hidden, const float* __restrict__ mask_g,
    const float* __restrict__ bq_g, const float* __restrict__ bk_g,
    const float* __restrict__ bv_g, const float* __restrict__ table_g,
    const bf16* __restrict__ pkw, float* __restrict__ out)
{
    __shared__ __align__(16) unsigned char sm[SMEM_BYTES];

    const int tid  = threadIdx.x;
    const int b    = blockIdx.x;
    const int widx = b & 63;
    const float* hbase = hidden + (size_t)b * (NTOK * 256);
    const float* mbase = mask_g + widx * 2401;

    // ---- cooperative staging: x window fp32->bf16 (swizzled), tab -------
    for (int c4 = tid; c4 < 3136; c4 += 256) {      // 49*256/4 chunks
        int row = c4 >> 6;
        int col = (c4 & 63) << 2;                   // 8B-aligned dest
        f32x4 v = *(const f32x4*)(hbase + row * 256 + col);
        union { bf16 h[4]; unsigned long long u; } p;
        p.h[0] = (bf16)v[0]; p.h[1] = (bf16)v[1];
        p.h[2] = (bf16)v[2]; p.h[3] = (bf16)v[3];
        *(unsigned long long*)(sm + XB_OFF(row, col)) = p.u;
    }
    for (int i = tid; i < 1352; i += 256)
        *(bf16*)(sm + TAB_BASE + 2 * i) = (bf16)table_g[i];
    __syncthreads();   // the ONLY block-wide barrier

    const int wave = tid >> 6;
    const int L    = tid & 63;
    const int quad = L >> 4;
    const int cc   = L & 15;
    const int WB   = WB_BASE + wave * WB_SIZE;

    int arow[4];
#pragma unroll
    for (int mt = 0; mt < 4; ++mt) {
        int r = 16 * mt + cc;
        arow[mt] = (r > 48) ? 48 : r;           // clamped rows discarded later
    }

    // ---- per-head pipeline: wave w -> heads {w, w+4} -------------------
    for (int hp = 0; hp < 2; ++hp) {
        const int h = wave + 4 * hp;

        // one projection pass: 2 output-col groups (hf), 32 acc regs peak.
        // vtr selects the transposed scatter (v -> vt[dim][token]).
        auto proj = [&](int t, int base, const float* __restrict__ bias_g,
                        bool vtr) {
            f32x4 acc[2][4];
#pragma unroll
            for (int hf = 0; hf < 2; ++hf)
#pragma unroll
                for (int mt = 0; mt < 4; ++mt)
                    acc[hf][mt] = (f32x4){0.f, 0.f, 0.f, 0.f};
            const bf16* bp0 = pkw + (((t * 16 + (h * 2 + 0)) * 8) << 9) + L * 8;
            const bf16* bp1 = pkw + (((t * 16 + (h * 2 + 1)) * 8) << 9) + L * 8;
#pragma unroll 2
            for (int kk = 0; kk < 8; ++kk) {
                bf16x8 a[4];
#pragma unroll
                for (int mt = 0; mt < 4; ++mt)
                    a[mt] = *(const bf16x8*)(sm + XB_OFF(arow[mt], kk * 32 + quad * 8));
                bf16x8 b0 = *(const bf16x8*)(bp0 + (kk << 9));
                bf16x8 b1 = *(const bf16x8*)(bp1 + (kk << 9));
#pragma unroll
                for (int mt = 0; mt < 4; ++mt) acc[0][mt] = mfma16(a[mt], b0, acc[0][mt]);
#pragma unroll
                for (int mt = 0; mt < 4; ++mt) acc[1][mt] = mfma16(a[mt], b1, acc[1][mt]);
            }
#pragma unroll
            for (int hf = 0; hf < 2; ++hf) {
                const float bias = bias_g[h * 32 + hf * 16 + cc];
                const int d = hf * 16 + cc;
#pragma unroll
                for (int mt = 0; mt < 4; ++mt)
#pragma unroll
                    for (int j = 0; j < 4; ++j) {
                        int row = 16 * mt + 4 * quad + j;   // D layout: row=(lane>>4)*4+reg
                        bf16 val = (bf16)(acc[hf][mt][j] + bias);
                        if (vtr) *(bf16*)(sm + VT_OFF(base, d, row)) = val;
                        else     *(bf16*)(sm + QK_OFF(base, row, d)) = val;
                    }
            }
        };
        proj(0, WB + QOFF,  bq_g, false);
        proj(1, WB + KOFF,  bk_g, false);
        proj(2, WB + VTOFF, bv_g, true);

        // ---- preload fragments: q/k fully into regs (enables P overlay),
        //      v-frags reused across all mt ------------------------------
        bf16x8 aq[4], bkf[4], bvf[2][2];
#pragma unroll
        for (int mt = 0; mt < 4; ++mt)
            aq[mt] = *(const bf16x8*)(sm + QK_OFF(WB + QOFF, 16 * mt + cc, quad * 8));
#pragma unroll
        for (int nt = 0; nt < 4; ++nt)
            bkf[nt] = *(const bf16x8*)(sm + QK_OFF(WB + KOFF, 16 * nt + cc, quad * 8));
#pragma unroll
        for (int kk = 0; kk < 2; ++kk)
#pragma unroll
            for (int nt = 0; nt < 2; ++nt)
                bvf[kk][nt] = *(const bf16x8*)(sm + VT_OFF(WB + VTOFF, 16 * nt + cc,
                                                           kk * 32 + quad * 8));

        // ---- streamed per-16-row-block: scores -> softmax -> PV -> store
        float* op = out + (size_t)b * (NTOK * 256) + h * 32;
        const f32x4 z = (f32x4){0.f, 0.f, 0.f, 0.f};
#pragma unroll
        for (int mt = 0; mt < 4; ++mt) {
            f32x4 s[4];
#pragma unroll
            for (int nt = 0; nt < 4; ++nt)
                s[nt] = mfma16(aq[mt], bkf[nt], z);

            float linv[4];
#pragma unroll
            for (int j = 0; j < 4; ++j) {
                const int r = 16 * mt + 4 * quad + j;
                // inline rel-pos row coord (was pr[16]: 16 persistent VGPRs)
                const int rh  = (r * 9363) >> 16;           // r/7 for r<64
                const int prv = 13 * rh + (r - 7 * rh);
                const float* mrow = mbase + r * 49;
                float vals[4];
#pragma unroll
                for (int nt = 0; nt < 4; ++nt) {
                    const int c = 16 * nt + cc;
                    float sc = s[nt][j] * SCALE;
                    if (r < 49 && c < 49) {
                        const int ch  = (c * 9363) >> 16;
                        const int idx = prv - (13 * ch + (c - 7 * ch)) + 84;
                        sc += (float)*(const bf16*)(sm + TAB_BASE + ((idx << 3) + h) * 2)
                            + mrow[c];                       // global fp32, L1-hot
                    } else {
                        sc = -1e30f;
                    }
                    vals[nt] = sc;
                }
                float mx = fmaxf(fmaxf(vals[0], vals[1]), fmaxf(vals[2], vals[3]));
                mx = fmaxf(mx, __shfl_xor(mx, 1));
                mx = fmaxf(mx, __shfl_xor(mx, 2));
                mx = fmaxf(mx, __shfl_xor(mx, 4));
                mx = fmaxf(mx, __shfl_xor(mx, 8));
                float sum = 0.f;
#pragma unroll
                for (int nt = 0; nt < 4; ++nt) {
                    float e = __expf(vals[nt] - mx);   // masked cols -> 0
                    sum += e;
                    *(bf16*)(sm + P_OFF(WB + POFF, r, 16 * nt + cc)) = (bf16)e;
                }
                sum += __shfl_xor(sum, 1);
                sum += __shfl_xor(sum, 2);
                sum += __shfl_xor(sum, 4);
                sum += __shfl_xor(sum, 8);
                linv[j] = 1.0f / sum;
            }

            // PV for this 16-row block (P rows complete; same-wave
            // ds_write->ds_read ordered by compiler lgkmcnt)
            bf16x8 ap0 = *(const bf16x8*)(sm + P_OFF(WB + POFF, 16 * mt + cc, quad * 8));
            bf16x8 ap1 = *(const bf16x8*)(sm + P_OFF(WB + POFF, 16 * mt + cc, 32 + quad * 8));
            f32x4 o0 = z, o1 = z;
            o0 = mfma16(ap0, bvf[0][0], o0);
            o1 = mfma16(ap0, bvf[0][1], o1);
            o0 = mfma16(ap1, bvf[1][0], o0);
            o1 = mfma16(ap1, bvf[1][1], o1);

#pragma unroll
            for (int j = 0; j < 4; ++j) {
                const int r = 16 * mt + 4 * quad + j;
                if (r < 49) {
                    op[(size_t)r * 256 + cc]      = o0[j] * linv[j];
                    op[(size_t)r * 256 + 16 + cc] = o1[j] * linv[j];
                }
            }
        }
        // Fence the WAR hazard: next head's projection ds_writes must not
        // pass this head's P/vt ds_reads.
        asm volatile("s_waitcnt lgkmcnt(0)" ::: "memory");
    }
}

// --------------------------------------------------------------------------
extern "C" void kernel_launch(void* const* d_in, const int* in_sizes, int n_in,
                              void* d_out, int out_size, void* d_ws, size_t ws_size,
                              hipStream_t stream) {
    const float* hidden = (const float*)d_in[0];   // [4096,49,256]
    const float* mask   = (const float*)d_in[1];   // [64,49,49]
    const float* wq     = (const float*)d_in[2];   // [256,256]
    const float* bq     = (const float*)d_in[3];   // [256]
    const float* wk     = (const float*)d_in[4];
    const float* bk     = (const float*)d_in[5];
    const float* wv     = (const float*)d_in[6];
    const float* bv     = (const float*)d_in[7];
    const float* tab    = (const float*)d_in[8];   // [169,8]
    float* out = (float*)d_out;
    bf16* pkw = (bf16*)d_ws;                       // 393,216 B repacked weights

    repack_w<<<768, 256, 0, stream>>>(wq, wk, wv, pkw);
    swin_attn<<<4096, 256, 0, stream>>>(hidden, mask, bq, bk, bv, tab, pkw, out);
}

// Round 9
// 777.765 us; speedup vs baseline: 1.5084x; 1.2894x over previous
//
#include <hip/hip_runtime.h>
#include <hip/hip_bf16.h>

// TFSwinSelfAttention fused kernel for MI355X (gfx950).
// Shapes: B=4096 windows, N=49 tokens, D=256 = 8 heads x 32.
// fp32 in/out; internal bf16 MFMA compute (fp32 accum) within harness tol.
//
// Round-11 (honest registers + kill the softmax latency chain):
//   r7/r8 evidence: (256,2) makes the backend clamp arch VGPRs to 128
//   (over-squeeze) -> ~90 regs/thread of loop-resident spill (WRITE 586MB),
//   while Occ 23% is LDS-capped (77KB -> 2 blocks/CU) regardless. r6's
//   honest demand was ~268 total (228 arch + ~40 acc) — only ~12 over the
//   2-waves/SIMD budget of 256. r8's structure is ~30 leaner but was never
//   measured unclamped. So:
//   1. PLAIN __launch_bounds__(256): no clamp, no spill; leaner structure
//      should land <=256 total -> 2 waves/SIMD naturally (LDS allows 2
//      blocks/CU = 8 waves/CU).
//   2. Precomputed bm[widx][h][64][64] = rel-bias + mask, -1e30 padding
//      (4MB bf16 in d_ws, L2-resident, built by a setup kernel): the
//      softmax inner loop's {LDS tab gather (bank-conflict scatter) +
//      mask VMEM + idx VALU chain + r/c branch} collapse to ONE bf16
//      L2-hot load. Also removes tab staging (LDS 77,312->74,240) and
//      ~15 regs of pointers/branch state.
//   Watch: WRITE == 200,704 KB (no spill) AND Occ ~22 = success. Occ ~12
//   => total regs still >256 -> next round restructures to 2-wave blocks.
//
// Carried from r8: window staged once/block to LDS bf16 (swizzled);
// 3-pass projection (32-reg acc peak); per-wave XOR-swizzled q/k[64][32],
// P[64][64] overlays q+k (aq/bkf preloaded BEFORE P writes - required),
// vt[32][64]; streamed per-16-row tail; single block barrier; end-of-head
// lgkmcnt fence for the WAR hazard.

typedef __bf16 bf16;
typedef __attribute__((ext_vector_type(8))) __bf16 bf16x8;
typedef __attribute__((ext_vector_type(4))) float f32x4;

__device__ __forceinline__ f32x4 mfma16(bf16x8 a, bf16x8 b, f32x4 c) {
    return __builtin_amdgcn_mfma_f32_16x16x32_bf16(a, b, c, 0, 0, 0);
}

// --------------------------------------------------------------------------
// Kernel 0: repack fp32 weights into bf16 B-fragment order (unchanged).
// packed[((t*16 + nt)*8 + kk)*512 + L*8 + j] = W_t[kk*32 + (L>>4)*8 + j][nt*16 + (L&15)]
__global__ void repack_w(const float* __restrict__ wq, const float* __restrict__ wk,
                         const float* __restrict__ wv, bf16* __restrict__ pk) {
    int i = blockIdx.x * 256 + threadIdx.x;      // 0 .. 3*65536-1
    int t = i >> 16;
    int r = i & 65535;
    int kr = r >> 8, nc = r & 255;
    const float* w = (t == 0) ? wq : (t == 1) ? wk : wv;
    int nt = nc >> 4;
    int kk = kr >> 5;
    int Ln = (((kr >> 3) & 3) << 4) | (nc & 15);
    int j  = kr & 7;
    pk[(((t * 16 + nt) * 8 + kk) << 9) + Ln * 8 + j] = (bf16)w[r];
}

// --------------------------------------------------------------------------
// Kernel 0b: combined rel-pos-bias + shifted-window-mask table.
// bm[widx][h][r][c] (r,c padded to 64) = tab[relidx(r,c)][h] + mask[widx][r][c]
// for r,c < 49; else -1e30 (=> exp -> 0 exactly; dead rows give e=1, discarded).
__global__ void build_bm(const float* __restrict__ tab, const float* __restrict__ mask,
                         bf16* __restrict__ bm) {
    int i = blockIdx.x * 256 + threadIdx.x;      // [64][8][64][64] = 2,097,152
    int c = i & 63, r = (i >> 6) & 63, h = (i >> 12) & 7, w = i >> 15;
    float v = -1e30f;
    if (r < 49 && c < 49) {
        int rh = r / 7, rw = r - 7 * rh;
        int ch = c / 7, cw = c - 7 * ch;
        int idx = (rh - ch + 6) * 13 + (rw - cw + 6);
        v = tab[idx * 8 + h] + mask[w * 2401 + r * 49 + c];
    }
    bm[i] = (bf16)v;
}

// --------------------------------------------------------------------------
#define NTOK 49
#define SCALE 0.17677669529663687f   // 1/sqrt(32)

// LDS blob layout (bytes).
#define XB_BASE   0            // bf16[49][256] swizzled  = 25,088
#define WB_BASE   25088        // 4 waves x 12,288        = 49,152
#define WB_SIZE   12288
#define QOFF      0            // bf16[64][32] swz        =  4,096
#define KOFF      4096         // bf16[64][32] swz        =  4,096
#define POFF      0            // bf16[64][64] swz, overlays q+k = 8,192
#define VTOFF     8192         // bf16[32][64] swz        =  4,096
#define SMEM_BYTES 74240       // 2 blocks/CU with ~15KB slack

// swizzle: byte ^= ((row&7)<<4); 16B granules move atomically.
#define XB_OFF(r,c)      (XB_BASE + ((((r) << 9) + ((c) << 1)) ^ (((r) & 7) << 4)))
#define QK_OFF(base,r,d) ((base) + ((((r) << 6) + ((d) << 1)) ^ (((r) & 7) << 4)))
#define P_OFF(base,r,c)  ((base) + ((((r) << 7) + ((c) << 1)) ^ (((r) & 7) << 4)))
#define VT_OFF(base,d,t) ((base) + ((((d) << 7) + ((t) << 1)) ^ (((d) & 7) << 4)))

__global__ __launch_bounds__(256)   // plain: honest allocation, no clamp-spill
void swin_attn(
    const float* __restrict__ hidden,
    const float* __restrict__ bq_g, const float* __restrict__ bk_g,
    const float* __restrict__ bv_g,
    const bf16* __restrict__ pkw, const bf16* __restrict__ bm,
    float* __restrict__ out)
{
    __shared__ __align__(16) unsigned char sm[SMEM_BYTES];

    const int tid  = threadIdx.x;
    const int b    = blockIdx.x;
    const int widx = b & 63;
    const float* hbase = hidden + (size_t)b * (NTOK * 256);

    // ---- cooperative staging: x window fp32->bf16 (swizzled) ------------
    for (int c4 = tid; c4 < 3136; c4 += 256) {      // 49*256/4 chunks
        int row = c4 >> 6;
        int col = (c4 & 63) << 2;                   // 8B-aligned dest
        f32x4 v = *(const f32x4*)(hbase + row * 256 + col);
        union { bf16 h[4]; unsigned long long u; } p;
        p.h[0] = (bf16)v[0]; p.h[1] = (bf16)v[1];
        p.h[2] = (bf16)v[2]; p.h[3] = (bf16)v[3];
        *(unsigned long long*)(sm + XB_OFF(row, col)) = p.u;
    }
    __syncthreads();   // the ONLY block-wide barrier

    const int wave = tid >> 6;
    const int L    = tid & 63;
    const int quad = L >> 4;
    const int cc   = L & 15;
    const int WB   = WB_BASE + wave * WB_SIZE;

    int arow[4];
#pragma unroll
    for (int mt = 0; mt < 4; ++mt) {
        int r = 16 * mt + cc;
        arow[mt] = (r > 48) ? 48 : r;           // clamped rows discarded later
    }

    // ---- per-head pipeline: wave w -> heads {w, w+4} -------------------
    for (int hp = 0; hp < 2; ++hp) {
        const int h = wave + 4 * hp;

        // one projection pass: 2 output-col groups (hf), 32 acc regs peak.
        auto proj = [&](int t, int base, const float* __restrict__ bias_g,
                        bool vtr) {
            f32x4 acc[2][4];
#pragma unroll
            for (int hf = 0; hf < 2; ++hf)
#pragma unroll
                for (int mt = 0; mt < 4; ++mt)
                    acc[hf][mt] = (f32x4){0.f, 0.f, 0.f, 0.f};
            const bf16* bp0 = pkw + (((t * 16 + (h * 2 + 0)) * 8) << 9) + L * 8;
            const bf16* bp1 = pkw + (((t * 16 + (h * 2 + 1)) * 8) << 9) + L * 8;
#pragma unroll 2
            for (int kk = 0; kk < 8; ++kk) {
                bf16x8 a[4];
#pragma unroll
                for (int mt = 0; mt < 4; ++mt)
                    a[mt] = *(const bf16x8*)(sm + XB_OFF(arow[mt], kk * 32 + quad * 8));
                bf16x8 b0 = *(const bf16x8*)(bp0 + (kk << 9));
                bf16x8 b1 = *(const bf16x8*)(bp1 + (kk << 9));
#pragma unroll
                for (int mt = 0; mt < 4; ++mt) acc[0][mt] = mfma16(a[mt], b0, acc[0][mt]);
#pragma unroll
                for (int mt = 0; mt < 4; ++mt) acc[1][mt] = mfma16(a[mt], b1, acc[1][mt]);
            }
#pragma unroll
            for (int hf = 0; hf < 2; ++hf) {
                const float bias = bias_g[h * 32 + hf * 16 + cc];
                const int d = hf * 16 + cc;
#pragma unroll
                for (int mt = 0; mt < 4; ++mt)
#pragma unroll
                    for (int j = 0; j < 4; ++j) {
                        int row = 16 * mt + 4 * quad + j;   // D layout: row=(lane>>4)*4+reg
                        bf16 val = (bf16)(acc[hf][mt][j] + bias);
                        if (vtr) *(bf16*)(sm + VT_OFF(base, d, row)) = val;
                        else     *(bf16*)(sm + QK_OFF(base, row, d)) = val;
                    }
            }
        };
        proj(0, WB + QOFF,  bq_g, false);
        proj(1, WB + KOFF,  bk_g, false);
        proj(2, WB + VTOFF, bv_g, true);

        // ---- preload fragments: q/k fully into regs BEFORE P overlay
        //      writes (required); v-frags reused across all mt -----------
        bf16x8 aq[4], bkf[4], bvf[2][2];
#pragma unroll
        for (int mt = 0; mt < 4; ++mt)
            aq[mt] = *(const bf16x8*)(sm + QK_OFF(WB + QOFF, 16 * mt + cc, quad * 8));
#pragma unroll
        for (int nt = 0; nt < 4; ++nt)
            bkf[nt] = *(const bf16x8*)(sm + QK_OFF(WB + KOFF, 16 * nt + cc, quad * 8));
#pragma unroll
        for (int kk = 0; kk < 2; ++kk)
#pragma unroll
            for (int nt = 0; nt < 2; ++nt)
                bvf[kk][nt] = *(const bf16x8*)(sm + VT_OFF(WB + VTOFF, 16 * nt + cc,
                                                           kk * 32 + quad * 8));

        // per-(widx,h) combined bias+mask slice: [64][64] bf16, L2-hot
        const bf16* bmh = bm + ((((widx << 3) + h) << 12));

        // ---- streamed per-16-row-block: scores -> softmax -> PV -> store
        float* op = out + (size_t)b * (NTOK * 256) + h * 32;
        const f32x4 z = (f32x4){0.f, 0.f, 0.f, 0.f};
#pragma unroll
        for (int mt = 0; mt < 4; ++mt) {
            f32x4 s[4];
#pragma unroll
            for (int nt = 0; nt < 4; ++nt)
                s[nt] = mfma16(aq[mt], bkf[nt], z);

            float linv[4];
#pragma unroll
            for (int j = 0; j < 4; ++j) {
                const int r = 16 * mt + 4 * quad + j;
                const bf16* bmr = bmh + (r << 6) + cc;
                float vals[4];
#pragma unroll
                for (int nt = 0; nt < 4; ++nt)     // one L2-hot bf16 load; no branch
                    vals[nt] = s[nt][j] * SCALE + (float)bmr[nt << 4];
                float mx = fmaxf(fmaxf(vals[0], vals[1]), fmaxf(vals[2], vals[3]));
                mx = fmaxf(mx, __shfl_xor(mx, 1));
                mx = fmaxf(mx, __shfl_xor(mx, 2));
                mx = fmaxf(mx, __shfl_xor(mx, 4));
                mx = fmaxf(mx, __shfl_xor(mx, 8));
                float sum = 0.f;
#pragma unroll
                for (int nt = 0; nt < 4; ++nt) {
                    float e = __expf(vals[nt] - mx);   // masked cols -> 0 exactly
                    sum += e;
                    *(bf16*)(sm + P_OFF(WB + POFF, r, 16 * nt + cc)) = (bf16)e;
                }
                sum += __shfl_xor(sum, 1);
                sum += __shfl_xor(sum, 2);
                sum += __shfl_xor(sum, 4);
                sum += __shfl_xor(sum, 8);
                linv[j] = 1.0f / sum;
            }

            // PV for this 16-row block (P rows complete; same-wave
            // ds_write->ds_read ordered by compiler lgkmcnt)
            bf16x8 ap0 = *(const bf16x8*)(sm + P_OFF(WB + POFF, 16 * mt + cc, quad * 8));
            bf16x8 ap1 = *(const bf16x8*)(sm + P_OFF(WB + POFF, 16 * mt + cc, 32 + quad * 8));
            f32x4 o0 = z, o1 = z;
            o0 = mfma16(ap0, bvf[0][0], o0);
            o1 = mfma16(ap0, bvf[0][1], o1);
            o0 = mfma16(ap1, bvf[1][0], o0);
            o1 = mfma16(ap1, bvf[1][1], o1);

#pragma unroll
            for (int j = 0; j < 4; ++j) {
                const int r = 16 * mt + 4 * quad + j;
                if (r < 49) {
                    op[(size_t)r * 256 + cc]      = o0[j] * linv[j];
                    op[(size_t)r * 256 + 16 + cc] = o1[j] * linv[j];
                }
            }
        }
        // Fence the WAR hazard: next head's projection ds_writes must not
        // pass this head's P/vt ds_reads.
        asm volatile("s_waitcnt lgkmcnt(0)" ::: "memory");
    }
}

// --------------------------------------------------------------------------
extern "C" void kernel_launch(void* const* d_in, const int* in_sizes, int n_in,
                              void* d_out, int out_size, void* d_ws, size_t ws_size,
                              hipStream_t stream) {
    const float* hidden = (const float*)d_in[0];   // [4096,49,256]
    const float* mask   = (const float*)d_in[1];   // [64,49,49]
    const float* wq     = (const float*)d_in[2];   // [256,256]
    const float* bq     = (const float*)d_in[3];   // [256]
    const float* wk     = (const float*)d_in[4];
    const float* bk     = (const float*)d_in[5];
    const float* wv     = (const float*)d_in[6];
    const float* bv     = (const float*)d_in[7];
    const float* tab    = (const float*)d_in[8];   // [169,8]
    float* out = (float*)d_out;
    bf16* pkw = (bf16*)d_ws;                       // 393,216 B repacked weights
    bf16* bm  = (bf16*)((char*)d_ws + 393216);     // 4,194,304 B combined bias+mask

    repack_w<<<768, 256, 0, stream>>>(wq, wk, wv, pkw);
    build_bm<<<8192, 256, 0, stream>>>(tab, mask, bm);
    swin_attn<<<4096, 256, 0, stream>>>(hidden, bq, bk, bv, pkw, bm, out);
}

// Round 10
// 606.155 us; speedup vs baseline: 1.9354x; 1.2831x over previous
//
#include <hip/hip_runtime.h>
#include <hip/hip_bf16.h>

// TFSwinSelfAttention fused kernel for MI355X (gfx950).
// Shapes: B=4096 windows, N=49 tokens, D=256 = 8 heads x 32.
// fp32 in/out; internal bf16 MFMA compute (fp32 accum) within harness tol.
//
// Round-12 (clamp the lean structure):
//   9-round VGPR->Occ table: arch 128 -> 22-23%; arch {164,176,228} -> ~12%.
//   Model: occupancy quantum = arch + AGPR-block total; MFMA accumulators
//   sit in a separate AGPR allocation (~64-96) on top of arch. 164+acc
//   rounds past 256 -> 1 wave/SIMD. Clamping to 128 arch fits 256 total ->
//   2 waves/SIMD; r7/r8's clamp spilled only because their NON-accumulator
//   live state (mask/tab ptrs, idx chain, branch state) exceeded 128.
//   r9's bm-table removed exactly that state. So:
//   1. __launch_bounds__(256, 2) on the r9 structure (expect no/min spill).
//   2. Insurance: bvf[2][2] preload (16 arch regs across the tail) demoted
//      into the mt loop — re-read 4x/head from LDS (conflict-free, cheap).
//   Watch: WRITE ~= 200,704 KB AND Occ ~22 = success; WRITE ballooning =>
//   non-acc live still > 128 -> next round restructures the tail.
//
// Carried from r9: bm[widx][h][64][64] combined bias+mask table (4MB d_ws,
// L2-hot, one bf16 load in softmax); window staged once/block to LDS bf16
// (swizzled); 3-pass projection (32-reg acc peak); per-wave XOR-swizzled
// q/k[64][32], P[64][64] overlays q+k (aq/bkf preloaded BEFORE P writes —
// required); vt[32][64]; streamed per-16-row tail; single block barrier;
// end-of-head lgkmcnt fence for the WAR hazard.

typedef __bf16 bf16;
typedef __attribute__((ext_vector_type(8))) __bf16 bf16x8;
typedef __attribute__((ext_vector_type(4))) float f32x4;

__device__ __forceinline__ f32x4 mfma16(bf16x8 a, bf16x8 b, f32x4 c) {
    return __builtin_amdgcn_mfma_f32_16x16x32_bf16(a, b, c, 0, 0, 0);
}

// --------------------------------------------------------------------------
// Kernel 0: repack fp32 weights into bf16 B-fragment order (unchanged).
// packed[((t*16 + nt)*8 + kk)*512 + L*8 + j] = W_t[kk*32 + (L>>4)*8 + j][nt*16 + (L&15)]
__global__ void repack_w(const float* __restrict__ wq, const float* __restrict__ wk,
                         const float* __restrict__ wv, bf16* __restrict__ pk) {
    int i = blockIdx.x * 256 + threadIdx.x;      // 0 .. 3*65536-1
    int t = i >> 16;
    int r = i & 65535;
    int kr = r >> 8, nc = r & 255;
    const float* w = (t == 0) ? wq : (t == 1) ? wk : wv;
    int nt = nc >> 4;
    int kk = kr >> 5;
    int Ln = (((kr >> 3) & 3) << 4) | (nc & 15);
    int j  = kr & 7;
    pk[(((t * 16 + nt) * 8 + kk) << 9) + Ln * 8 + j] = (bf16)w[r];
}

// --------------------------------------------------------------------------
// Kernel 0b: combined rel-pos-bias + shifted-window-mask table.
// bm[widx][h][r][c] (r,c padded to 64) = tab[relidx(r,c)][h] + mask[widx][r][c]
// for r,c < 49; else -1e30 (=> exp -> 0 exactly; dead rows give e=1, discarded).
__global__ void build_bm(const float* __restrict__ tab, const float* __restrict__ mask,
                         bf16* __restrict__ bm) {
    int i = blockIdx.x * 256 + threadIdx.x;      // [64][8][64][64] = 2,097,152
    int c = i & 63, r = (i >> 6) & 63, h = (i >> 12) & 7, w = i >> 15;
    float v = -1e30f;
    if (r < 49 && c < 49) {
        int rh = r / 7, rw = r - 7 * rh;
        int ch = c / 7, cw = c - 7 * ch;
        int idx = (rh - ch + 6) * 13 + (rw - cw + 6);
        v = tab[idx * 8 + h] + mask[w * 2401 + r * 49 + c];
    }
    bm[i] = (bf16)v;
}

// --------------------------------------------------------------------------
#define NTOK 49
#define SCALE 0.17677669529663687f   // 1/sqrt(32)

// LDS blob layout (bytes).
#define XB_BASE   0            // bf16[49][256] swizzled  = 25,088
#define WB_BASE   25088        // 4 waves x 12,288        = 49,152
#define WB_SIZE   12288
#define QOFF      0            // bf16[64][32] swz        =  4,096
#define KOFF      4096         // bf16[64][32] swz        =  4,096
#define POFF      0            // bf16[64][64] swz, overlays q+k = 8,192
#define VTOFF     8192         // bf16[32][64] swz        =  4,096
#define SMEM_BYTES 74240       // 2 blocks/CU with ~15KB slack

// swizzle: byte ^= ((row&7)<<4); 16B granules move atomically.
#define XB_OFF(r,c)      (XB_BASE + ((((r) << 9) + ((c) << 1)) ^ (((r) & 7) << 4)))
#define QK_OFF(base,r,d) ((base) + ((((r) << 6) + ((d) << 1)) ^ (((r) & 7) << 4)))
#define P_OFF(base,r,c)  ((base) + ((((r) << 7) + ((c) << 1)) ^ (((r) & 7) << 4)))
#define VT_OFF(base,d,t) ((base) + ((((d) << 7) + ((t) << 1)) ^ (((d) & 7) << 4)))

__global__ __launch_bounds__(256, 2)   // 2 waves/EU: arch<=128 + acc block fits 256 total
void swin_attn(
    const float* __restrict__ hidden,
    const float* __restrict__ bq_g, const float* __restrict__ bk_g,
    const float* __restrict__ bv_g,
    const bf16* __restrict__ pkw, const bf16* __restrict__ bm,
    float* __restrict__ out)
{
    __shared__ __align__(16) unsigned char sm[SMEM_BYTES];

    const int tid  = threadIdx.x;
    const int b    = blockIdx.x;
    const int widx = b & 63;
    const float* hbase = hidden + (size_t)b * (NTOK * 256);

    // ---- cooperative staging: x window fp32->bf16 (swizzled) ------------
    for (int c4 = tid; c4 < 3136; c4 += 256) {      // 49*256/4 chunks
        int row = c4 >> 6;
        int col = (c4 & 63) << 2;                   // 8B-aligned dest
        f32x4 v = *(const f32x4*)(hbase + row * 256 + col);
        union { bf16 h[4]; unsigned long long u; } p;
        p.h[0] = (bf16)v[0]; p.h[1] = (bf16)v[1];
        p.h[2] = (bf16)v[2]; p.h[3] = (bf16)v[3];
        *(unsigned long long*)(sm + XB_OFF(row, col)) = p.u;
    }
    __syncthreads();   // the ONLY block-wide barrier

    const int wave = tid >> 6;
    const int L    = tid & 63;
    const int quad = L >> 4;
    const int cc   = L & 15;
    const int WB   = WB_BASE + wave * WB_SIZE;

    int arow[4];
#pragma unroll
    for (int mt = 0; mt < 4; ++mt) {
        int r = 16 * mt + cc;
        arow[mt] = (r > 48) ? 48 : r;           // clamped rows discarded later
    }

    // ---- per-head pipeline: wave w -> heads {w, w+4} -------------------
    for (int hp = 0; hp < 2; ++hp) {
        const int h = wave + 4 * hp;

        // one projection pass: 2 output-col groups (hf), 32 acc regs peak.
        auto proj = [&](int t, int base, const float* __restrict__ bias_g,
                        bool vtr) {
            f32x4 acc[2][4];
#pragma unroll
            for (int hf = 0; hf < 2; ++hf)
#pragma unroll
                for (int mt = 0; mt < 4; ++mt)
                    acc[hf][mt] = (f32x4){0.f, 0.f, 0.f, 0.f};
            const bf16* bp0 = pkw + (((t * 16 + (h * 2 + 0)) * 8) << 9) + L * 8;
            const bf16* bp1 = pkw + (((t * 16 + (h * 2 + 1)) * 8) << 9) + L * 8;
#pragma unroll 2
            for (int kk = 0; kk < 8; ++kk) {
                bf16x8 a[4];
#pragma unroll
                for (int mt = 0; mt < 4; ++mt)
                    a[mt] = *(const bf16x8*)(sm + XB_OFF(arow[mt], kk * 32 + quad * 8));
                bf16x8 b0 = *(const bf16x8*)(bp0 + (kk << 9));
                bf16x8 b1 = *(const bf16x8*)(bp1 + (kk << 9));
#pragma unroll
                for (int mt = 0; mt < 4; ++mt) acc[0][mt] = mfma16(a[mt], b0, acc[0][mt]);
#pragma unroll
                for (int mt = 0; mt < 4; ++mt) acc[1][mt] = mfma16(a[mt], b1, acc[1][mt]);
            }
#pragma unroll
            for (int hf = 0; hf < 2; ++hf) {
                const float bias = bias_g[h * 32 + hf * 16 + cc];
                const int d = hf * 16 + cc;
#pragma unroll
                for (int mt = 0; mt < 4; ++mt)
#pragma unroll
                    for (int j = 0; j < 4; ++j) {
                        int row = 16 * mt + 4 * quad + j;   // D layout: row=(lane>>4)*4+reg
                        bf16 val = (bf16)(acc[hf][mt][j] + bias);
                        if (vtr) *(bf16*)(sm + VT_OFF(base, d, row)) = val;
                        else     *(bf16*)(sm + QK_OFF(base, row, d)) = val;
                    }
            }
        };
        proj(0, WB + QOFF,  bq_g, false);
        proj(1, WB + KOFF,  bk_g, false);
        proj(2, WB + VTOFF, bv_g, true);

        // ---- preload q/k fragments into regs BEFORE P overlay writes
        //      (required for correctness of the overlay) ------------------
        bf16x8 aq[4], bkf[4];
#pragma unroll
        for (int mt = 0; mt < 4; ++mt)
            aq[mt] = *(const bf16x8*)(sm + QK_OFF(WB + QOFF, 16 * mt + cc, quad * 8));
#pragma unroll
        for (int nt = 0; nt < 4; ++nt)
            bkf[nt] = *(const bf16x8*)(sm + QK_OFF(WB + KOFF, 16 * nt + cc, quad * 8));

        // per-(widx,h) combined bias+mask slice: [64][64] bf16, L2-hot
        const bf16* bmh = bm + ((((widx << 3) + h) << 12));

        // ---- streamed per-16-row-block: scores -> softmax -> PV -> store
        float* op = out + (size_t)b * (NTOK * 256) + h * 32;
        const f32x4 z = (f32x4){0.f, 0.f, 0.f, 0.f};
#pragma unroll
        for (int mt = 0; mt < 4; ++mt) {
            f32x4 s[4];
#pragma unroll
            for (int nt = 0; nt < 4; ++nt)
                s[nt] = mfma16(aq[mt], bkf[nt], z);

            float linv[4];
#pragma unroll
            for (int j = 0; j < 4; ++j) {
                const int r = 16 * mt + 4 * quad + j;
                const bf16* bmr = bmh + (r << 6) + cc;
                float vals[4];
#pragma unroll
                for (int nt = 0; nt < 4; ++nt)     // one L2-hot bf16 load; no branch
                    vals[nt] = s[nt][j] * SCALE + (float)bmr[nt << 4];
                float mx = fmaxf(fmaxf(vals[0], vals[1]), fmaxf(vals[2], vals[3]));
                mx = fmaxf(mx, __shfl_xor(mx, 1));
                mx = fmaxf(mx, __shfl_xor(mx, 2));
                mx = fmaxf(mx, __shfl_xor(mx, 4));
                mx = fmaxf(mx, __shfl_xor(mx, 8));
                float sum = 0.f;
#pragma unroll
                for (int nt = 0; nt < 4; ++nt) {
                    float e = __expf(vals[nt] - mx);   // masked cols -> 0 exactly
                    sum += e;
                    *(bf16*)(sm + P_OFF(WB + POFF, r, 16 * nt + cc)) = (bf16)e;
                }
                sum += __shfl_xor(sum, 1);
                sum += __shfl_xor(sum, 2);
                sum += __shfl_xor(sum, 4);
                sum += __shfl_xor(sum, 8);
                linv[j] = 1.0f / sum;
            }

            // PV for this 16-row block. bvf read per-mt from LDS (demoted
            // from a 16-reg preload: arch-side pressure insurance; reads
            // are conflict-free and amortized by the 4 MFMAs).
            bf16x8 ap0 = *(const bf16x8*)(sm + P_OFF(WB + POFF, 16 * mt + cc, quad * 8));
            bf16x8 ap1 = *(const bf16x8*)(sm + P_OFF(WB + POFF, 16 * mt + cc, 32 + quad * 8));
            f32x4 o0 = z, o1 = z;
            o0 = mfma16(ap0, *(const bf16x8*)(sm + VT_OFF(WB + VTOFF, cc,      quad * 8)), o0);
            o1 = mfma16(ap0, *(const bf16x8*)(sm + VT_OFF(WB + VTOFF, 16 + cc, quad * 8)), o1);
            o0 = mfma16(ap1, *(const bf16x8*)(sm + VT_OFF(WB + VTOFF, cc,      32 + quad * 8)), o0);
            o1 = mfma16(ap1, *(const bf16x8*)(sm + VT_OFF(WB + VTOFF, 16 + cc, 32 + quad * 8)), o1);

#pragma unroll
            for (int j = 0; j < 4; ++j) {
                const int r = 16 * mt + 4 * quad + j;
                if (r < 49) {
                    op[(size_t)r * 256 + cc]      = o0[j] * linv[j];
                    op[(size_t)r * 256 + 16 + cc] = o1[j] * linv[j];
                }
            }
        }
        // Fence the WAR hazard: next head's projection ds_writes must not
        // pass this head's P/vt ds_reads.
        asm volatile("s_waitcnt lgkmcnt(0)" ::: "memory");
    }
}

// --------------------------------------------------------------------------
extern "C" void kernel_launch(void* const* d_in, const int* in_sizes, int n_in,
                              void* d_out, int out_size, void* d_ws, size_t ws_size,
                              hipStream_t stream) {
    const float* hidden = (const float*)d_in[0];   // [4096,49,256]
    const float* mask   = (const float*)d_in[1];   // [64,49,49]
    const float* wq     = (const float*)d_in[2];   // [256,256]
    const float* bq     = (const float*)d_in[3];   // [256]
    const float* wk     = (const float*)d_in[4];
    const float* bk     = (const float*)d_in[5];
    const float* wv     = (const float*)d_in[6];
    const float* bv     = (const float*)d_in[7];
    const float* tab    = (const float*)d_in[8];   // [169,8]
    float* out = (float*)d_out;
    bf16* pkw = (bf16*)d_ws;                       // 393,216 B repacked weights
    bf16* bm  = (bf16*)((char*)d_ws + 393216);     // 4,194,304 B combined bias+mask

    repack_w<<<768, 256, 0, stream>>>(wq, wk, wv, pkw);
    build_bm<<<8192, 256, 0, stream>>>(tab, mask, bm);
    swin_attn<<<4096, 256, 0, stream>>>(hidden, bq, bk, bv, pkw, bm, out);
}